// Round 16
// baseline (59.436 us; speedup 1.0000x reference)
//
#include <hip/hip_runtime.h>
#include <math.h>

// ---------------------------------------------------------------------------
// ConvLogicNetCIFAR forward. R16 = R15 + explicit ILP (software pipelining).
// R15 evidence: VALUBusy 34%, LDS pipe ~35%, VGPR=52 -> NO pipe saturated;
// the 16-wave block is dependency-latency-bound and the compiler kept little
// MLP in flight. Fix: 2 outputs per loop iteration in stages 1-3 (issue all
// 32 tap dwords, then eval both trees), 2-way batching in stage 4, FC index
// prefetch. VGPR headroom is ample (~512/wave at 4 waves/SIMD).
// Structure unchanged (best, 58.95us): 256 blocks x 1024 thr = 2/batch elem,
// redundant tower + FC split 5/5; dup h2 cells, paired-row ds_read2 taps;
// S3d dup [512][4][5] aliases XB; 6 barriers.
// Gate: c0+c1*a+c2*b+c3*ab, c=softmax(w)@COEF.
// Tree quirk: off=2^lvl-1 -> level0 rows0..3, level1 rows1..2, level2 row3.
// ---------------------------------------------------------------------------

typedef _Float16 h16;
typedef _Float16 h2 __attribute__((ext_vector_type(2)));

__constant__ float c_coef_tbl[16][4] = {
    {0, 0, 0, 0}, {0, 0, 0, 1}, {0, 1, 0, -1}, {0, 1, 0, 0},
    {0, 0, 1, -1}, {0, 0, 1, 0}, {0, 1, 1, -2}, {0, 1, 1, -1},
    {1, -1, -1, 1}, {1, -1, -1, 2}, {1, 0, -1, 0}, {1, 0, -1, 1},
    {1, -1, 0, 0}, {1, -1, 0, 1}, {1, 0, 0, -1}, {1, 0, 0, 0}};

__device__ __forceinline__ float4 softmax_coef(const float* __restrict__ wr) {
  float m = -1e30f;
#pragma unroll
  for (int k = 0; k < 16; ++k) m = fmaxf(m, wr[k]);
  float e[16], s = 0.f;
#pragma unroll
  for (int k = 0; k < 16; ++k) { e[k] = __expf(wr[k] - m); s += e[k]; }
  float inv = 1.f / s;
  float c0 = 0.f, c1 = 0.f, c2 = 0.f, c3 = 0.f;
#pragma unroll
  for (int k = 0; k < 16; ++k) {
    c0 += e[k] * c_coef_tbl[k][0];
    c1 += e[k] * c_coef_tbl[k][1];
    c2 += e[k] * c_coef_tbl[k][2];
    c3 += e[k] * c_coef_tbl[k][3];
  }
  return make_float4(c0 * inv, c1 * inv, c2 * inv, c3 * inv);
}

__device__ __forceinline__ float gate_eval(float4 c, float a, float b) {
  return c.x + c.y * a + c.z * b + c.w * (a * b);
}
__device__ __forceinline__ float4 dec_cf(uint2 u) {
  h2 p0, p1;
  *(unsigned*)&p0 = u.x;
  *(unsigned*)&p1 = u.y;
  return make_float4((float)p0[0], (float)p0[1], (float)p1[0], (float)p1[1]);
}
__device__ __forceinline__ h2 gateh(const h2* c, h2 a, h2 b) {
  return c[0] + c[1] * a + c[2] * b + c[3] * (a * b);
}
__device__ __forceinline__ h2 tree8(const h2 (&ch)[4][4], const h2* lv) {
  h2 t0 = gateh(ch[0], lv[0], lv[1]);
  h2 t1 = gateh(ch[1], lv[2], lv[3]);
  h2 t2 = gateh(ch[2], lv[4], lv[5]);
  h2 t3 = gateh(ch[3], lv[6], lv[7]);
  h2 u0 = gateh(ch[1], t0, t1);
  h2 u1 = gateh(ch[2], t2, t3);
  return gateh(ch[3], u0, u1);
}
__device__ __forceinline__ h2 pkmax(h2 a, h2 b) {
  h2 r;
  r[0] = a[0] > b[0] ? a[0] : b[0];
  r[1] = a[1] > b[1] ? a[1] : b[1];
  return r;
}
__device__ __forceinline__ void splat_ch(const float4* __restrict__ coef, int oc,
                                         h2 (&ch)[4][4]) {
#pragma unroll
  for (int r = 0; r < 4; ++r) {
    float4 c = coef[oc * 4 + r];
    _Float16 x0 = (_Float16)c.x, x1 = (_Float16)c.y,
             x2 = (_Float16)c.z, x3 = (_Float16)c.w;
    ch[r][0][0] = x0; ch[r][0][1] = x0;
    ch[r][1][0] = x1; ch[r][1][1] = x1;
    ch[r][2][0] = x2; ch[r][2][1] = x2;
    ch[r][3][0] = x3; ch[r][3][1] = x3;
  }
}

// prep: g<71680 FC tree (o=g/7, s=g%7 -> fp16 coefs mcoefh[o*28+s*4], u16
// midx16[o*8..]); g in [71680,78464) conv gate coefs float4
// (w1[0,128) w2[128,640) w3[640,2688) w4[2688,6784); gate gg -> row oc*7+(gg&3)).
__global__ void prep_all(const float* __restrict__ w1, const float* __restrict__ w2,
                         const float* __restrict__ w3, const float* __restrict__ w4,
                         const float* __restrict__ fw1, const float* __restrict__ fw2,
                         const float* __restrict__ fw3,
                         const int* __restrict__ ca1, const int* __restrict__ cb1,
                         const int* __restrict__ ca2, const int* __restrict__ cb2,
                         const int* __restrict__ ca3, const int* __restrict__ cb3,
                         float4* __restrict__ coefC,
                         unsigned short* __restrict__ midx16,
                         _Float16* __restrict__ mcoefh) {
  int g = blockIdx.x * blockDim.x + threadIdx.x;
  if (g < 71680) {
    int o = g / 7;
    int s = g - o * 7;
    float4 c;
    if (s < 4) {
      int k = (s < 2) ? ca3[o] : cb3[o];
      int j = (s & 1) ? cb2[k] : ca2[k];
      midx16[o * 8 + s * 2]     = (unsigned short)ca1[j];
      midx16[o * 8 + s * 2 + 1] = (unsigned short)cb1[j];
      c = softmax_coef(fw1 + j * 16);
    } else if (s < 6) {
      int k = (s == 4) ? ca3[o] : cb3[o];
      c = softmax_coef(fw2 + k * 16);
    } else {
      c = softmax_coef(fw3 + o * 16);
    }
    _Float16* mc = mcoefh + o * 28 + s * 4;
    mc[0] = (_Float16)c.x; mc[1] = (_Float16)c.y;
    mc[2] = (_Float16)c.z; mc[3] = (_Float16)c.w;
  } else if (g < 78464) {
    int gg = g - 71680;
    int base = gg;
    const float* w;
    if (gg < 128)       {             w = w1; }
    else if (gg < 640)  { gg -= 128;  w = w2; }
    else if (gg < 2688) { gg -= 640;  w = w3; }
    else                { gg -= 2688; w = w4; }
    coefC[base] = softmax_coef(w + ((gg >> 2) * 7 + (gg & 3)) * 16);
  }
}

// Conv tree + orpool, LDS->LDS dup cells, paired-row reads, 2 outputs per
// iteration (explicit ILP: 32 loads issued before any tree eval).
template <int C, int H, int W, int OC, int IPS, int OPS, int OW, int VH>
__device__ void stage(const h2* __restrict__ in, h2* __restrict__ outD,
                      const int* __restrict__ leaf,
                      const float4* __restrict__ coef, int tid) {
  constexpr int Wp = W + 2;
  constexpr int PH = H / 2, PW = W / 2;
  constexpr int NPOS = PH * PW;
  constexpr int TPO = 1024 / OC;
  constexpr int ITER = NPOS / TPO;   // 8 for all stages

  int oc = tid / TPO;
  int lane = tid % TPO;

  int toff[8];
#pragma unroll
  for (int l = 0; l < 8; ++l) {
    int k = leaf[oc * 8 + l];
    int cc = k / 9;
    int p = k - 9 * cc;
    int di = p / 3;
    int dj = p - 3 * di;
    toff[l] = cc * IPS + di * Wp + dj;
  }
  h2 ch[4][4];
  splat_ch(coef, oc, ch);

  h16* oh = (h16*)outD;
#pragma unroll
  for (int it = 0; it < ITER; it += 2) {
    int pos0 = lane + it * TPO;
    int pos1 = pos0 + TPO;
    int pw0 = pos0 % PW, ph0 = pos0 / PW;
    int pw1 = pos1 % PW, ph1 = pos1 / PW;
    int pb0 = (2 * ph0) * Wp + 2 * pw0;
    int pb1 = (2 * ph1) * Wp + 2 * pw1;
    h2 A0[8], B0[8], A1[8], B1[8];
#pragma unroll
    for (int l = 0; l < 8; ++l) {
      const h2* p0 = in + toff[l] + pb0;
      const h2* p1 = in + toff[l] + pb1;
      A0[l] = p0[0];
      B0[l] = p0[Wp];
      A1[l] = p1[0];
      B1[l] = p1[Wp];
    }
    h2 pm0 = pkmax(tree8(ch, A0), tree8(ch, B0));
    h2 pm1 = pkmax(tree8(ch, A1), tree8(ch, B1));
    _Float16 v0 = pm0[0] > pm0[1] ? pm0[0] : pm0[1];
    _Float16 v1 = pm1[0] > pm1[1] ? pm1[0] : pm1[1];
    int cell0 = oc * OPS + (ph0 + VH) * OW + (pw0 + 1);
    int cell1 = oc * OPS + (ph1 + VH) * OW + (pw1 + 1);
    oh[2 * cell0] = v0;
    oh[2 * cell0 - 1] = v0;
    oh[2 * cell1] = v1;
    oh[2 * cell1 - 1] = v1;
  }
}

// Megakernel: 256 blocks x 1024 threads; pair (bid>>1)=batch elem, role=bid&1.
__global__ __launch_bounds__(1024) void mega(
    const float* __restrict__ x, const float4* __restrict__ coefC,
    const int* __restrict__ l1, const int* __restrict__ l2,
    const int* __restrict__ l3, const int* __restrict__ l4,
    const unsigned short* __restrict__ midx16,
    const _Float16* __restrict__ mcoefh, float* __restrict__ out) {
  __shared__ __align__(16) h2 XB[9 * 1157];    // 41,652B
  __shared__ __align__(16) h2 S1[32 * 325];    // 41,600B
  __shared__ __align__(16) h2 S2[128 * 101];   // 51,712B
  __shared__ __align__(16) h16 S4[1024 * 4];   //  8,192B
  __shared__ float red[16][5];
  h2* S3d = XB;  // stage3 dup out [512][4][5] = 10,240 h2, aliases dead XB
  int tid = threadIdx.x;
  int b = blockIdx.x >> 1;
  int role = blockIdx.x & 1;

  // ---- phase 0: zero S1/S2 + binarize x -> XB dup-padded ----
  {
    float4* z1 = (float4*)S1;
    float4* z2 = (float4*)S2;
    float4 zz = make_float4(0.f, 0.f, 0.f, 0.f);
    for (int i = tid; i < 2600; i += 1024) z1[i] = zz;
    for (int i = tid; i < 3232; i += 1024) z2[i] = zz;
  }
  const float* xg = x + b * 3072;
  for (int cell = tid; cell < 9 * 1157; cell += 1024) {
    int c9 = cell / 1157;
    int rem = cell - c9 * 1157;
    if (rem >= 1156) continue;
    int i = rem / 34, j = rem - 34 * (rem / 34);
    int th = c9 / 3, c = c9 - 3 * th;
    float thr = (float)(th + 1) * 0.25f;
    _Float16 lo = (_Float16)0, hi = (_Float16)0;
    if (i >= 1 && i <= 32) {
      const float* row = xg + c * 1024 + (i - 1) * 32;
      if (j >= 1 && j <= 32) lo = (_Float16)((row[j - 1] > thr) ? 1.f : 0.f);
      if (j <= 31)           hi = (_Float16)((row[j] > thr) ? 1.f : 0.f);
    }
    XB[cell] = h2{lo, hi};
  }
  __syncthreads();

  // ---- stage 1: XB -> S1 ----
  stage<9, 32, 32, 32, 1157, 325, 18, 1>(XB, S1, l1, coefC, tid);
  __syncthreads();

  // ---- stage 2: S1 -> S2; also zero S3d's col-0 pad cells (XB now dead) ----
  for (int i = tid; i < 2048; i += 1024)
    S3d[(i >> 2) * 20 + (i & 3) * 5] = h2{(_Float16)0, (_Float16)0};
  stage<32, 16, 16, 128, 325, 101, 10, 1>(S1, S2, l2, coefC + 128, tid);
  __syncthreads();

  // ---- stage 3: S2 -> S3d dup [512][4][5] ----
  stage<128, 8, 8, 512, 101, 20, 5, 0>(S2, S3d, l3, coefC + 640, tid);
  __syncthreads();

  // ---- stage 4: S3d dup reads, 2 positions batched, 1 thread/oc ----
  {
    int oc = tid;
    int boff[8], dI[8];
#pragma unroll
    for (int l = 0; l < 8; ++l) {
      int k = l4[oc * 8 + l];
      int cc = k / 9;
      int p = k - 9 * cc;
      int di = p / 3;
      int dj = p - 3 * di;
      dI[l] = di;
      boff[l] = cc * 20 + dj;
    }
    h2 ch[4][4];
    splat_ch(coefC + 2688, oc, ch);
#pragma unroll
    for (int pp = 0; pp < 2; ++pp) {   // pos pair (2pp, 2pp+1): same ph
      int ph = pp;
      h2 lv0[2][8], lv1[2][8];
#pragma unroll
      for (int py = 0; py < 2; ++py) {
#pragma unroll
        for (int l = 0; l < 8; ++l) {
          int i = 2 * ph + py + dI[l] - 1;
          h2 z = h2{(_Float16)0, (_Float16)0};
          lv0[py][l] = ((unsigned)i < 4u) ? S3d[boff[l] + i * 5 + 0] : z;
          lv1[py][l] = ((unsigned)i < 4u) ? S3d[boff[l] + i * 5 + 2] : z;
        }
      }
      h2 pm0 = pkmax(tree8(ch, lv0[0]), tree8(ch, lv0[1]));
      h2 pm1 = pkmax(tree8(ch, lv1[0]), tree8(ch, lv1[1]));
      S4[oc * 4 + ph * 2 + 0] = pm0[0] > pm0[1] ? pm0[0] : pm0[1];
      S4[oc * 4 + ph * 2 + 1] = pm1[0] > pm1[1] ? pm1[0] : pm1[1];
    }
  }
  __syncthreads();

  // ---- fused FC, 5 classes (role-split), index prefetch ----
  const uint4* mi = (const uint4*)midx16;
  const uint2* mc = (const uint2*)mcoefh;
  int wid = tid >> 6;
  uint4 I[5];
#pragma unroll
  for (int k = 0; k < 5; ++k) I[k] = mi[(role * 5 + k) * 1024 + tid];
#pragma unroll
  for (int k = 0; k < 5; ++k) {
    int o = (role * 5 + k) * 1024 + tid;
    const uint2* cfp = mc + o * 7;
    float L0 = gate_eval(dec_cf(cfp[0]), (float)S4[I[k].x & 0xffff], (float)S4[I[k].x >> 16]);
    float L1 = gate_eval(dec_cf(cfp[1]), (float)S4[I[k].y & 0xffff], (float)S4[I[k].y >> 16]);
    float L2 = gate_eval(dec_cf(cfp[2]), (float)S4[I[k].z & 0xffff], (float)S4[I[k].z >> 16]);
    float L3 = gate_eval(dec_cf(cfp[3]), (float)S4[I[k].w & 0xffff], (float)S4[I[k].w >> 16]);
    float M0 = gate_eval(dec_cf(cfp[4]), L0, L1);
    float M1 = gate_eval(dec_cf(cfp[5]), L2, L3);
    float y = gate_eval(dec_cf(cfp[6]), M0, M1);
#pragma unroll
    for (int m = 32; m > 0; m >>= 1) y += __shfl_xor(y, m, 64);
    if ((tid & 63) == 0) red[wid][k] = y;
  }
  __syncthreads();
  if (tid < 5) {
    float s = 0.f;
#pragma unroll
    for (int w = 0; w < 16; ++w) s += red[w][tid];
    out[b * 10 + role * 5 + tid] = s * 0.1f;
  }
}

extern "C" void kernel_launch(void* const* d_in, const int* in_sizes, int n_in,
                              void* d_out, int out_size, void* d_ws, size_t ws_size,
                              hipStream_t stream) {
  const float* x   = (const float*)d_in[0];
  const float* w1  = (const float*)d_in[1];
  const float* w2  = (const float*)d_in[2];
  const float* w3  = (const float*)d_in[3];
  const float* w4  = (const float*)d_in[4];
  const float* fw1 = (const float*)d_in[5];
  const float* fw2 = (const float*)d_in[6];
  const float* fw3 = (const float*)d_in[7];
  const int* l1  = (const int*)d_in[8];
  const int* l2  = (const int*)d_in[9];
  const int* l3  = (const int*)d_in[10];
  const int* l4  = (const int*)d_in[11];
  const int* ca1 = (const int*)d_in[12];
  const int* cb1 = (const int*)d_in[13];
  const int* ca2 = (const int*)d_in[14];
  const int* cb2 = (const int*)d_in[15];
  const int* ca3 = (const int*)d_in[16];
  const int* cb3 = (const int*)d_in[17];

  char* ws = (char*)d_ws;
  float4*         coefC  = (float4*)ws;                      // 108,544 B
  unsigned short* midx16 = (unsigned short*)(ws + 108544);   // 163,840 B
  _Float16*       mcoefh = (_Float16*)(ws + 108544 + 163840);// 573,440 B

  prep_all<<<307, 256, 0, stream>>>(w1, w2, w3, w4, fw1, fw2, fw3,
                                    ca1, cb1, ca2, cb2, ca3, cb3,
                                    coefC, midx16, mcoefh);
  mega<<<256, 1024, 0, stream>>>(x, coefC, l1, l2, l3, l4, midx16, mcoefh,
                                 (float*)d_out);
}